// Round 16
// baseline (34.859 us; speedup 1.0000x reference)
//
#include <hip/hip_runtime.h>

#define NJ     62
#define NV     14522
#define NCORE  28
#define KPAD   256    // 62*4 = 248 padded to 256 (512 B per row)
#define OUTF   (NV * 3)        // 43566
#define MT     908             // m-tiles of 16 rows

typedef __attribute__((ext_vector_type(8))) short short8v;
typedef __attribute__((ext_vector_type(4))) short short4v;
typedef __attribute__((ext_vector_type(4))) float floatx4;
typedef __attribute__((ext_vector_type(2))) float floatx2;

static __device__ inline short f2bf(float x) {
    unsigned u = __float_as_uint(x);
    unsigned r = (u + 0x7fffu + ((u >> 16) & 1u)) >> 16;
    return (short)r;
}

// pack 8 floats -> 8 bf16 (RNE) via v_cvt_pk_bf16_f32
static __device__ inline short8v pack8(float a0, float a1, float a2, float a3,
                                       float a4, float a5, float a6, float a7) {
    union { unsigned u[4]; short8v v; } p;
    asm("v_cvt_pk_bf16_f32 %0, %1, %2" : "=v"(p.u[0]) : "v"(a0), "v"(a1));
    asm("v_cvt_pk_bf16_f32 %0, %1, %2" : "=v"(p.u[1]) : "v"(a2), "v"(a3));
    asm("v_cvt_pk_bf16_f32 %0, %1, %2" : "=v"(p.u[2]) : "v"(a4), "v"(a5));
    asm("v_cvt_pk_bf16_f32 %0, %1, %2" : "=v"(p.u[3]) : "v"(a6), "v"(a7));
    return p.v;
}

// ---------------------------------------------------------------------------
// Single fused kernel. Grid 768 x 256 thr (3 blocks/CU, 3 waves/SIMD).
// Block (yy = bid/48, inner = bid%48):
//  PHASE 1 (FK): the block's 16 batches (4 per wave, sequential) computed
//    in-block; G' written as bf16 directly into the swizzled LDS B-slab
//    (48 rows x 512B). inner==0 blocks also write Jout. ~48x redundant
//    across blocks but ~2us wall and removes a launch + Bt roundtrip.
//  PHASE 2 (GEMM, r12-identical): wave w = stripe s = inner*4+w, 4-5
//    contiguous m16-tiles; A built on the fly from W/vt; B frags via
//    swizzled ds_read_b128; wave-private epi transpose (overlaid on FK
//    scratch); coalesced float2 stores.
// LDS: B 24K + FK scratch 23.3K (epi 12.8K overlays it) = 48.4 KB.
// ---------------------------------------------------------------------------
__global__ __launch_bounds__(256, 3) void fused_kernel(
    const float* __restrict__ thetas,  // (B, K*3)
    const float* __restrict__ blc,     // (B, NCORE)
    const float* __restrict__ cbl,     // (B, 1)
    const float* __restrict__ trans,   // (B, 3)
    const float* __restrict__ scale,   // (B,)
    const float* __restrict__ tpose,   // (K, 3)
    const int*   __restrict__ parents, // (K,)
    const int*   __restrict__ mapper,  // (K,)
    const float* __restrict__ W,       // (V, 62) fp32
    const float* __restrict__ vt,      // (V, 3)  fp32
    float* __restrict__ out)           // V_final (B,V,3) ++ J_out (B,K,3)
{
    __shared__ __align__(16) char pool[24576 + 11904 + 11904];  // 48.4 KB
    char*  ldsB    = pool;                            // 24 KB B slab
    float* Asm     = (float*)(pool + 24576);          // [4][62][12] FK scratch
    float* Gsm     = (float*)(pool + 24576 + 11904);  // [4][62][12]
    float* epi_all = (float*)(pool + 24576);          // 12.8 KB, post-FK overlay

    const int tid  = threadIdx.x;
    const int wave = tid >> 6;
    const int lane = tid & 63;
    const int lrow = lane & 15;
    const int lk   = lane >> 4;
    const int yy    = blockIdx.x / 48;          // 0..15 (y-group)
    const int inner = blockIdx.x - yy * 48;     // 0..47
    const int s     = inner * 4 + wave;         // stripe 0..191
    const int start  = s * 4 + (s < 140 ? s : 140);
    const int ntiles = 4 + (s < 140 ? 1 : 0);   // 140*5 + 52*4 = 908
    const int b0 = yy * 16;
    float* Jout = out + (size_t)256 * NV * 3;

    // ======================= PHASE 1: in-block FK =======================
    {
        const int k = lane;
        int p = 0, mp = -1;
        float jx = 0.f, jy = 0.f, jz = 0.f, dx = 0.f, dy = 0.f, dz = 0.f;
        if (k < NJ) {
            p  = parents[k];
            mp = mapper[k];
            jx = tpose[k * 3 + 0]; jy = tpose[k * 3 + 1]; jz = tpose[k * 3 + 2];
            dx = jx - tpose[p * 3 + 0];
            dy = jy - tpose[p * 3 + 1];
            dz = jz - tpose[p * 3 + 2];
        }
        const int depth = (k < NJ) ? (31 - __clz((unsigned)(k + 1))) : 99;
        float* As = Asm + (wave * NJ) * 12;
        float* Gs = Gsm + (wave * NJ) * 12;

        for (int it = 0; it < 4; ++it) {
            const int bb = b0 + wave * 4 + it;
            if (k < NJ) {
                const float tz = thetas[(bb * NJ + k) * 3 + 0];
                const float ty = thetas[(bb * NJ + k) * 3 + 1];
                const float tx = thetas[(bb * NJ + k) * 3 + 2];
                const float cx = cosf(tx), sx = sinf(tx);
                const float cy = cosf(ty), sy = sinf(ty);
                const float cz = cosf(tz), sz = sinf(tz);
                float f;
                if (k == 0)        f = 1.0f;
                else if (k == 1)   f = cbl[bb];
                else if (mp < 0)   f = 1.0f;
                else               f = 2.0f / (1.0f + expf(-blc[bb * NCORE + mp] * 0.2f));
                float ox, oy, oz;
                if (k == 0) { ox = jx; oy = jy; oz = jz; }
                else        { ox = dx * f; oy = dy * f; oz = dz * f; }
                float* a = As + k * 12;
                a[0] = cz * cy;                 a[1] = cz * sy * sx - sz * cx;
                a[2] = sz * sx + cz * sy * cx;  a[3] = ox;
                a[4] = sz * cy;                 a[5] = cz * cx + sz * sy * sx;
                a[6] = sz * sy * cx - cz * sx;  a[7] = oy;
                a[8] = -sy;                     a[9] = cy * sx;
                a[10] = cy * cx;                a[11] = oz;
            }
            __syncthreads();
            if (k == 0) {
                #pragma unroll
                for (int j = 0; j < 12; ++j) Gs[j] = As[j];
            }
            __syncthreads();
            for (int d = 1; d <= 5; ++d) {
                if (depth == d) {
                    float gp[12], a[12], g[12];
                    #pragma unroll
                    for (int j = 0; j < 12; ++j) { gp[j] = Gs[p * 12 + j]; a[j] = As[k * 12 + j]; }
                    #pragma unroll
                    for (int i = 0; i < 3; ++i) {
                        #pragma unroll
                        for (int j = 0; j < 4; ++j) {
                            float ss = (j == 3) ? gp[i * 4 + 3] : 0.0f;
                            ss = fmaf(gp[i * 4 + 0], a[0 * 4 + j], ss);
                            ss = fmaf(gp[i * 4 + 1], a[1 * 4 + j], ss);
                            ss = fmaf(gp[i * 4 + 2], a[2 * 4 + j], ss);
                            g[i * 4 + j] = ss;
                        }
                    }
                    #pragma unroll
                    for (int j = 0; j < 12; ++j) Gs[k * 12 + j] = g[j];
                }
                __syncthreads();
            }

            // write B-slab rows (swizzled) + Jout
            if (k < NJ) {
                float g[12];
                #pragma unroll
                for (int j = 0; j < 12; ++j) g[j] = Gs[k * 12 + j];
                float np[3];
                np[0] = g[3]  - (g[0] * jx + g[1] * jy + g[2]  * jz);
                np[1] = g[7]  - (g[4] * jx + g[5] * jy + g[6]  * jz);
                np[2] = g[11] - (g[8] * jx + g[9] * jy + g[10] * jz);
                #pragma unroll
                for (int i = 0; i < 3; ++i) {
                    short4v o;
                    o[0] = f2bf(g[i * 4 + 0]);
                    o[1] = f2bf(g[i * 4 + 1]);
                    o[2] = f2bf(g[i * 4 + 2]);
                    o[3] = f2bf(np[i]);
                    const unsigned row = (unsigned)((wave * 4 + it) * 3 + i);
                    const unsigned off = row * 512 + (((unsigned)k * 8) ^ ((row & 7u) << 4));
                    *(short4v*)(ldsB + off) = o;
                }
                if (inner == 0) {
                    const float sc = scale[bb];
                    Jout[(bb * NJ + k) * 3 + 0] = fmaf(g[3],  sc, trans[bb * 3 + 0]);
                    Jout[(bb * NJ + k) * 3 + 1] = fmaf(g[7],  sc, trans[bb * 3 + 1]);
                    Jout[(bb * NJ + k) * 3 + 2] = fmaf(g[11], sc, trans[bb * 3 + 2]);
                }
            } else {
                // lanes 62,63: zero K-padding cols 248..255 (k*4 = 248/252)
                short4v z = {0, 0, 0, 0};
                #pragma unroll
                for (int i = 0; i < 3; ++i) {
                    const unsigned row = (unsigned)((wave * 4 + it) * 3 + i);
                    const unsigned off = row * 512 + (((unsigned)k * 8) ^ ((row & 7u) << 4));
                    *(short4v*)(ldsB + off) = z;
                }
            }
            __syncthreads();   // Asm/Gsm reuse next it; final: B-slab visible
        }
    }

    // ======================= PHASE 2: GEMM (r12) =======================
    float* epi = epi_all + wave * 800;          // 16 regions x 50 floats

    float sv[3], tv[3]; int eoff[3];
    #pragma unroll
    for (int nt = 0; nt < 3; ++nt) {
        const int n_loc = nt * 16 + lrow;
        const int bl = n_loc / 3, ii = n_loc - bl * 3;
        eoff[nt] = bl * 50 + ii;
        sv[nt] = scale[b0 + bl];
        tv[nt] = trans[(b0 + bl) * 3 + ii];
    }
    unsigned bofs[3], bxor[3];
    #pragma unroll
    for (int nt = 0; nt < 3; ++nt) {
        const unsigned brow = nt * 16 + lrow;
        bofs[nt] = brow * 512;
        bxor[nt] = (brow & 7u) << 4;
    }

    for (int t = 0; t < ntiles; ++t) {
        const int mtile = start + t;
        int vrow = mtile * 16 + lrow;
        if (vrow > NV - 1) vrow = NV - 1;           // pad rows: never stored
        const float hx = vt[vrow * 3 + 0];
        const float hy = vt[vrow * 3 + 1];
        const float hz = vt[vrow * 3 + 2];
        const float* Wr = W + (size_t)vrow * NJ;

        // A frags on the fly (8 scattered float2 + pack)
        short8v af[8];
        #pragma unroll
        for (int k8 = 0; k8 < 8; ++k8) {
            const int j0 = k8 * 8 + lk * 2;
            float w0 = 0.f, w1 = 0.f;
            if (j0 < NJ) {
                const floatx2 wv = *(const floatx2*)(Wr + j0);  // 8B-aligned
                w0 = wv[0]; w1 = wv[1];
            }
            af[k8] = pack8(w0 * hx, w0 * hy, w0 * hz, w0,
                           w1 * hx, w1 * hy, w1 * hz, w1);
        }

        // MFMA: B frags from LDS (swizzled ds_read_b128)
        floatx4 acc[3];
        #pragma unroll
        for (int nt = 0; nt < 3; ++nt) acc[nt] = (floatx4){0.f, 0.f, 0.f, 0.f};
        #pragma unroll
        for (int k8 = 0; k8 < 8; ++k8) {
            const unsigned cb = (unsigned)(k8 * 4 + lk) * 16;
            #pragma unroll
            for (int nt = 0; nt < 3; ++nt) {
                const short8v bf = *(const short8v*)(ldsB + bofs[nt] + (cb ^ bxor[nt]));
                acc[nt] = __builtin_amdgcn_mfma_f32_16x16x32_bf16(
                    af[k8], bf, acc[nt], 0, 0, 0);
            }
        }

        // epilogue transpose (wave-private region)
        #pragma unroll
        for (int nt = 0; nt < 3; ++nt) {
            #pragma unroll
            for (int r = 0; r < 4; ++r)
                epi[eoff[nt] + (lk * 4 + r) * 3] =
                    fmaf(acc[nt][r], sv[nt], tv[nt]);
        }

        // coalesced stores: 16 regions x 24 float2
        const int m48 = mtile * 48;
        const bool edge = (m48 + 48 > OUTF);
        #pragma unroll
        for (int it = 0; it < 6; ++it) {
            const int idx = it * 64 + lane;
            const int r = idx / 24, j = idx - r * 24;
            const floatx2 val = *(const floatx2*)&epi[r * 50 + 2 * j];
            const int pp = m48 + 2 * j;
            if (!edge || pp + 1 < OUTF)
                *(floatx2*)&out[(size_t)(b0 + r) * OUTF + pp] = val;
        }
    }
}

extern "C" void kernel_launch(void* const* d_in, const int* in_sizes, int n_in,
                              void* d_out, int out_size, void* d_ws, size_t ws_size,
                              hipStream_t stream)
{
    const float* thetas  = (const float*)d_in[0];
    const float* blc     = (const float*)d_in[1];
    const float* cbl     = (const float*)d_in[2];
    const float* trans   = (const float*)d_in[3];
    const float* scale   = (const float*)d_in[4];
    const float* vtempl  = (const float*)d_in[5];
    const float* tpose   = (const float*)d_in[6];
    const float* weights = (const float*)d_in[7];
    const int*   parents = (const int*)d_in[8];
    const int*   mapper  = (const int*)d_in[9];

    float* out = (float*)d_out;

    fused_kernel<<<768, 256, 0, stream>>>(
        thetas, blc, cbl, trans, scale, tpose, parents, mapper,
        weights, vtempl, out);
}

// Round 17
// 25.140 us; speedup vs baseline: 1.3866x; 1.3866x over previous
//
#include <hip/hip_runtime.h>

#define NJ     62
#define NV     14522
#define NCORE  28
#define KPAD   256    // 62*4 = 248 padded to 256 (512 B per row)
#define OUTF   (NV * 3)        // 43566
#define MT     908             // m-tiles of 16 rows
#define NSTR   192             // stripes: 140 of 5 tiles, 52 of 4

typedef __attribute__((ext_vector_type(8))) short short8v;
typedef __attribute__((ext_vector_type(4))) short short4v;
typedef __attribute__((ext_vector_type(4))) float floatx4;
typedef __attribute__((ext_vector_type(2))) float floatx2;

#define AS1(p) ((const __attribute__((address_space(1))) void*)(p))
#define AS3(p) ((__attribute__((address_space(3))) void*)(p))

#define SCHED0() __builtin_amdgcn_sched_barrier(0)
#define WAITVM0() do { SCHED0(); asm volatile("s_waitcnt vmcnt(0)" ::: "memory"); SCHED0(); } while (0)

static __device__ inline short f2bf(float x) {
    unsigned u = __float_as_uint(x);
    unsigned r = (u + 0x7fffu + ((u >> 16) & 1u)) >> 16;
    return (short)r;
}

// pack 8 floats -> 8 bf16 (RNE) via v_cvt_pk_bf16_f32
static __device__ inline short8v pack8(float a0, float a1, float a2, float a3,
                                       float a4, float a5, float a6, float a7) {
    union { unsigned u[4]; short8v v; } p;
    asm("v_cvt_pk_bf16_f32 %0, %1, %2" : "=v"(p.u[0]) : "v"(a0), "v"(a1));
    asm("v_cvt_pk_bf16_f32 %0, %1, %2" : "=v"(p.u[1]) : "v"(a2), "v"(a3));
    asm("v_cvt_pk_bf16_f32 %0, %1, %2" : "=v"(p.u[2]) : "v"(a4), "v"(a5));
    asm("v_cvt_pk_bf16_f32 %0, %1, %2" : "=v"(p.u[3]) : "v"(a6), "v"(a7));
    return p.v;
}

// XOR swizzle over 512B rows: involution; global SOURCE at staging and LDS
// read addresses (both-sides rule). Proven in r6.
static __device__ inline unsigned swz(unsigned off) {
    return off ^ (((off >> 9) & 7u) << 4);
}

// ---------------------------------------------------------------------------
// Kernel 1: forward kinematics. 64 blocks x 256 thr; wave w = batch
// blockIdx*4+w. Writes Jout (fp32) and Bt (bf16) in the PERMUTED K layout:
//   joint j, comps m=0..3 at K-pos q = 32*((j%16)/2) + 8*(j/16) + 4*(j%2) + m
// (inverse of the gemm's per-lane-contiguous W mapping).
// ---------------------------------------------------------------------------
__global__ __launch_bounds__(256) void fk_kernel(
    const float* __restrict__ thetas, const float* __restrict__ blc,
    const float* __restrict__ cbl, const float* __restrict__ trans,
    const float* __restrict__ scale, const float* __restrict__ tpose,
    const int* __restrict__ parents, const int* __restrict__ mapper,
    short* __restrict__ Bt, float* __restrict__ Jout)
{
    __shared__ float Asm[4][NJ][12];
    __shared__ float Gsm[4][NJ][12];

    const int w = threadIdx.x >> 6;
    const int b = blockIdx.x * 4 + w;
    const int k = threadIdx.x & 63;
    int p = 0;

    if (k < NJ) {
        p = parents[k];
        const float tz = thetas[(b * NJ + k) * 3 + 0];
        const float ty = thetas[(b * NJ + k) * 3 + 1];
        const float tx = thetas[(b * NJ + k) * 3 + 2];
        const float cx = cosf(tx), sx = sinf(tx);
        const float cy = cosf(ty), sy = sinf(ty);
        const float cz = cosf(tz), sz = sinf(tz);
        const float r00 = cz * cy;
        const float r01 = cz * sy * sx - sz * cx;
        const float r02 = sz * sx + cz * sy * cx;
        const float r10 = sz * cy;
        const float r11 = cz * cx + sz * sy * sx;
        const float r12 = sz * sy * cx - cz * sx;
        const float r20 = -sy;
        const float r21 = cy * sx;
        const float r22 = cy * cx;

        float f;
        const int m = mapper[k];
        if (k == 0)        f = 1.0f;
        else if (k == 1)   f = cbl[b];
        else if (m < 0)    f = 1.0f;
        else               f = 2.0f / (1.0f + expf(-blc[b * NCORE + m] * 0.2f));

        float ox, oy, oz;
        if (k == 0) {
            ox = tpose[0]; oy = tpose[1]; oz = tpose[2];
        } else {
            ox = (tpose[k * 3 + 0] - tpose[p * 3 + 0]) * f;
            oy = (tpose[k * 3 + 1] - tpose[p * 3 + 1]) * f;
            oz = (tpose[k * 3 + 2] - tpose[p * 3 + 2]) * f;
        }
        Asm[w][k][0] = r00; Asm[w][k][1] = r01; Asm[w][k][2]  = r02; Asm[w][k][3]  = ox;
        Asm[w][k][4] = r10; Asm[w][k][5] = r11; Asm[w][k][6]  = r12; Asm[w][k][7]  = oy;
        Asm[w][k][8] = r20; Asm[w][k][9] = r21; Asm[w][k][10] = r22; Asm[w][k][11] = oz;
    }
    __syncthreads();

    if (k == 0) {
        #pragma unroll
        for (int j = 0; j < 12; ++j) Gsm[w][0][j] = Asm[w][0][j];
    }
    __syncthreads();

    const int depth = (k < NJ) ? (31 - __clz((unsigned)(k + 1))) : 99;
    for (int d = 1; d <= 5; ++d) {
        if (depth == d) {
            float gp[12], a[12], g[12];
            #pragma unroll
            for (int j = 0; j < 12; ++j) { gp[j] = Gsm[w][p][j]; a[j] = Asm[w][k][j]; }
            #pragma unroll
            for (int i = 0; i < 3; ++i) {
                #pragma unroll
                for (int j = 0; j < 4; ++j) {
                    float s = (j == 3) ? gp[i * 4 + 3] : 0.0f;
                    s = fmaf(gp[i * 4 + 0], a[0 * 4 + j], s);
                    s = fmaf(gp[i * 4 + 1], a[1 * 4 + j], s);
                    s = fmaf(gp[i * 4 + 2], a[2 * 4 + j], s);
                    g[i * 4 + j] = s;
                }
            }
            #pragma unroll
            for (int j = 0; j < 12; ++j) Gsm[w][k][j] = g[j];
        }
        __syncthreads();
    }

    if (k < NJ) {
        float g[12];
        #pragma unroll
        for (int j = 0; j < 12; ++j) g[j] = Gsm[w][k][j];
        const float jx = tpose[k * 3 + 0];
        const float jy = tpose[k * 3 + 1];
        const float jz = tpose[k * 3 + 2];
        const float s  = scale[b];
        Jout[(b * NJ + k) * 3 + 0] = fmaf(g[3],  s, trans[b * 3 + 0]);
        Jout[(b * NJ + k) * 3 + 1] = fmaf(g[7],  s, trans[b * 3 + 1]);
        Jout[(b * NJ + k) * 3 + 2] = fmaf(g[11], s, trans[b * 3 + 2]);
        float np[3];
        np[0] = g[3]  - (g[0] * jx + g[1] * jy + g[2]  * jz);
        np[1] = g[7]  - (g[4] * jx + g[5] * jy + g[6]  * jz);
        np[2] = g[11] - (g[8] * jx + g[9] * jy + g[10] * jz);

        // permuted K position for this joint
        const int lkj = k >> 4;          // j / 16
        const int rr  = k & 15;
        const int qb  = 32 * (rr >> 1) + 8 * lkj + 4 * (rr & 1);
        #pragma unroll
        for (int i = 0; i < 3; ++i) {
            short4v o;
            o[0] = f2bf(g[i * 4 + 0]);
            o[1] = f2bf(g[i * 4 + 1]);
            o[2] = f2bf(g[i * 4 + 2]);
            o[3] = f2bf(np[i]);
            *(short4v*)&Bt[(size_t)(b * 3 + i) * KPAD + qb] = o;
        }
        if (k == 0) {   // zero K padding (joints 62,63 -> q 248..255)
            short4v z = {0, 0, 0, 0};
            #pragma unroll
            for (int i = 0; i < 3; ++i) {
                *(short4v*)&Bt[(size_t)(b * 3 + i) * KPAD + 248] = z;
                *(short4v*)&Bt[(size_t)(b * 3 + i) * KPAD + 252] = z;
            }
        }
    }
}

// ---------------------------------------------------------------------------
// Kernel 2: GEMM + epilogue — r12 (best) + gather fix:
//  - permuted K layout makes each lane's 16 W weights CONTIGUOUS:
//    4 coalesced float4 loads (full cache lines) instead of 8 scattered
//    float2 (16 lines each).
//  - W/vt prefetch for tile t+1 issued before tile t's MFMA phase.
//  - A frags built inline per k8 (VGPR ~115, cap 168: no spill).
// Grid 768 (3 blocks/CU, 3 waves/SIMD), 192 stripes x 16 y-groups.
// ---------------------------------------------------------------------------
__global__ __launch_bounds__(256, 3) void gemm_skin(
    const float* __restrict__ W,      // (V, 62) fp32
    const float* __restrict__ vt,     // (V, 3)  fp32
    const short* __restrict__ Bt,     // (768, KPAD) bf16, permuted K
    const float* __restrict__ scale,  // (B,)
    const float* __restrict__ trans,  // (B*3,)
    float* __restrict__ out)          // (B, V, 3)
{
    __shared__ __align__(16) char ldsB[48 * 512];       // 24 KB B slab
    __shared__ __align__(16) float epi_all[4 * 800];    // 12.8 KB epi

    const int tid  = threadIdx.x;
    const int wave = tid >> 6;
    const int lane = tid & 63;
    const int lrow = lane & 15;
    const int lk   = lane >> 4;
    const int yy    = blockIdx.x / 48;          // 0..15 (y-group)
    const int inner = blockIdx.x - yy * 48;     // 0..47
    const int s     = inner * 4 + wave;         // stripe 0..191
    const int start  = s * 4 + (s < 140 ? s : 140);
    const int ntiles = 4 + (s < 140 ? 1 : 0);   // 140*5 + 52*4 = 908
    const int b0 = yy * 16;
    float* epi = epi_all + wave * 800;          // 16 regions x 50 floats

    // ---- stage B slab into LDS once (global_load_lds, both-sides swizzle)
    {
        const char* Bsrc = (const char*)(Bt + (size_t)yy * 48 * KPAD);
        #pragma unroll
        for (int cc = 0; cc < 6; ++cc) {
            const unsigned Lb = (unsigned)(wave * 6144 + cc * 1024);
            __builtin_amdgcn_global_load_lds(AS1(Bsrc + swz(Lb + lane * 16)),
                                             AS3(ldsB + Lb), 16, 0, 0);
        }
    }

    // ---- per-thread invariants (while DMA in flight)
    float sv[3], tv[3]; int eoff[3];
    #pragma unroll
    for (int nt = 0; nt < 3; ++nt) {
        const int n_loc = nt * 16 + lrow;
        const int bl = n_loc / 3, ii = n_loc - bl * 3;
        eoff[nt] = bl * 50 + ii;
        sv[nt] = scale[b0 + bl];
        tv[nt] = trans[(b0 + bl) * 3 + ii];
    }
    unsigned bofs[3], bxor[3];
    #pragma unroll
    for (int nt = 0; nt < 3; ++nt) {
        const unsigned brow = nt * 16 + lrow;
        bofs[nt] = brow * 512;
        bxor[nt] = (brow & 7u) << 4;
    }

    // ---- prefetch tile 0's W (4 coalesced float4: 16 contiguous weights
    //      at W[row] + 16*lk) and vt row
    floatx4 wc[4]; float hcx, hcy, hcz;
    {
        int vrow = start * 16 + lrow;
        if (vrow > NV - 1) vrow = NV - 1;
        const float* Wb = W + (size_t)vrow * NJ + lk * 16;
        // lk==3: floats 48..63 of the row; 62,63 bleed into next row's
        // floats (in-bounds of the array; zeroed at use).
        wc[0] = *(const floatx4*)(Wb + 0);
        wc[1] = *(const floatx4*)(Wb + 4);
        wc[2] = *(const floatx4*)(Wb + 8);
        wc[3] = *(const floatx4*)(Wb + 12);
        hcx = vt[vrow * 3 + 0]; hcy = vt[vrow * 3 + 1]; hcz = vt[vrow * 3 + 2];
    }

    WAITVM0();
    __syncthreads();    // B slab resident; read-only hereafter

    for (int t = 0; t < ntiles; ++t) {
        // ---- issue prefetch for tile t+1 (latency hidden under MFMA/epi/store)
        floatx4 wn[4]; float hnx = 0.f, hny = 0.f, hnz = 0.f;
        if (t + 1 < ntiles) {
            int vr = (start + t + 1) * 16 + lrow;
            if (vr > NV - 1) vr = NV - 1;
            const float* Wb = W + (size_t)vr * NJ + lk * 16;
            wn[0] = *(const floatx4*)(Wb + 0);
            wn[1] = *(const floatx4*)(Wb + 4);
            wn[2] = *(const floatx4*)(Wb + 8);
            wn[3] = *(const floatx4*)(Wb + 12);
            hnx = vt[vr * 3 + 0]; hny = vt[vr * 3 + 1]; hnz = vt[vr * 3 + 2];
        } else {
            wn[0] = wn[1] = wn[2] = wn[3] = (floatx4){0.f, 0.f, 0.f, 0.f};
        }

        // ---- MFMA: A frag built inline per k8 from contiguous weights;
        //      B frags from LDS (swizzled ds_read_b128)
        floatx4 acc[3];
        #pragma unroll
        for (int nt = 0; nt < 3; ++nt) acc[nt] = (floatx4){0.f, 0.f, 0.f, 0.f};
        #pragma unroll
        for (int k8 = 0; k8 < 8; ++k8) {
            // joints 16*lk + 2*k8, +1  ->  wc[k8/2][2*(k8%2)], [..+1]
            float w0 = wc[k8 >> 1][2 * (k8 & 1)];
            float w1 = wc[k8 >> 1][2 * (k8 & 1) + 1];
            if (lk == 3 && k8 == 7) { w0 = 0.f; w1 = 0.f; }   // joints 62,63
            const short8v a = pack8(w0 * hcx, w0 * hcy, w0 * hcz, w0,
                                    w1 * hcx, w1 * hcy, w1 * hcz, w1);
            const unsigned cb = (unsigned)(k8 * 4 + lk) * 16;
            #pragma unroll
            for (int nt = 0; nt < 3; ++nt) {
                const short8v bf = *(const short8v*)(ldsB + bofs[nt] + (cb ^ bxor[nt]));
                acc[nt] = __builtin_amdgcn_mfma_f32_16x16x32_bf16(
                    a, bf, acc[nt], 0, 0, 0);
            }
        }

        // ---- epilogue transpose (wave-private region)
        #pragma unroll
        for (int nt = 0; nt < 3; ++nt) {
            #pragma unroll
            for (int r = 0; r < 4; ++r)
                epi[eoff[nt] + (lk * 4 + r) * 3] =
                    fmaf(acc[nt][r], sv[nt], tv[nt]);
        }

        // ---- coalesced stores: 16 regions x 24 float2
        const int m48 = (start + t) * 48;
        const bool edge = (m48 + 48 > OUTF);
        #pragma unroll
        for (int it = 0; it < 6; ++it) {
            const int idx = it * 64 + lane;
            const int r = idx / 24, j = idx - r * 24;
            const floatx2 val = *(const floatx2*)&epi[r * 50 + 2 * j];
            const int pp = m48 + 2 * j;
            if (!edge || pp + 1 < OUTF)
                *(floatx2*)&out[(size_t)(b0 + r) * OUTF + pp] = val;
        }

        // ---- rotate prefetch
        wc[0] = wn[0]; wc[1] = wn[1]; wc[2] = wn[2]; wc[3] = wn[3];
        hcx = hnx; hcy = hny; hcz = hnz;
    }
}

extern "C" void kernel_launch(void* const* d_in, const int* in_sizes, int n_in,
                              void* d_out, int out_size, void* d_ws, size_t ws_size,
                              hipStream_t stream)
{
    const float* thetas  = (const float*)d_in[0];
    const float* blc     = (const float*)d_in[1];
    const float* cbl     = (const float*)d_in[2];
    const float* trans   = (const float*)d_in[3];
    const float* scale   = (const float*)d_in[4];
    const float* vtempl  = (const float*)d_in[5];
    const float* tpose   = (const float*)d_in[6];
    const float* weights = (const float*)d_in[7];
    const int*   parents = (const int*)d_in[8];
    const int*   mapper  = (const int*)d_in[9];

    float* out  = (float*)d_out;
    float* Jout = out + (size_t)256 * NV * 3;

    short* Bt = (short*)d_ws;                    // 768*KPAD bf16 = 0.39 MB

    fk_kernel<<<64, 256, 0, stream>>>(thetas, blc, cbl, trans, scale, tpose,
                                      parents, mapper, Bt, Jout);
    gemm_skin<<<768, 256, 0, stream>>>(weights, vtempl, Bt, scale, trans, out);
}